// Round 1
// baseline (591.761 us; speedup 1.0000x reference)
//
#include <hip/hip_runtime.h>
#include <math.h>

#define Bb 128
#define Hh 4
#define Nn 8192
#define Dd 64

constexpr float BETA = 10.0f;
constexpr float EPSV = 1e-8f;

// d_out layout (flat float32, reference return order):
constexpr long long OFF_RC = 0;                              // read_combined (B,D)
constexpr long long OFF_RW = (long long)Bb * Dd;             // r_w (B,H,N)
constexpr long long OFF_NM = OFF_RW + (long long)Bb*Hh*Nn;   // new_memory (B,N,D)
constexpr long long OFF_WW = OFF_NM + (long long)Bb*Nn*Dd;   // w_w (B,H,N)

// ---------------------------------------------------------------------------
// K1: stream memory once. Per row: norm + 8 key dots (4 read + 4 write heads).
// Writes new_memory = 4*memory, and sims directly into the r_w / w_w output
// regions (same (B,H,N) shape — K2 overwrites them with the sparse weights).
// 16 lanes x float4 per row; butterfly reduce 9 partials over the 16-group.
// ---------------------------------------------------------------------------
__global__ __launch_bounds__(256) void k1_sims(
    const float* __restrict__ mem, const float* __restrict__ rkeys,
    const float* __restrict__ wkeys, float* __restrict__ out)
{
  __shared__ float keys[8 * 64];     // heads 0-3 read, 4-7 write
  __shared__ float knorm[8];
  __shared__ float sims[8][256];
  const int b = blockIdx.x >> 5;     // 32 chunks per batch
  const int c = blockIdx.x & 31;
  const int t = threadIdx.x;

  keys[t]       = rkeys[b * 256 + t];
  keys[256 + t] = wkeys[b * 256 + t];
  __syncthreads();
  if (t < 8) {
    float s = 0.f;
    for (int d = 0; d < 64; ++d) { float k = keys[t * 64 + d]; s += k * k; }
    knorm[t] = fmaxf(sqrtf(s), EPSV);
  }
  __syncthreads();

  const int g = t >> 4, q = t & 15;          // group (row), lane-in-group
  const float4* kvec = (const float4*)keys;  // kvec[h*16 + q]
  const int base = c * 256;

  for (int it = 0; it < 16; ++it) {
    const int n = base + it * 16 + g;
    const long long rowoff = ((long long)b * Nn + n) * Dd;
    float4 v = ((const float4*)(mem + rowoff))[q];
    float acc[9];
    acc[8] = v.x*v.x + v.y*v.y + v.z*v.z + v.w*v.w;   // norm^2 partial
#pragma unroll
    for (int h = 0; h < 8; ++h) {
      float4 k4 = kvec[h * 16 + q];
      acc[h] = v.x*k4.x + v.y*k4.y + v.z*k4.z + v.w*k4.w;
    }
#pragma unroll
    for (int off = 1; off < 16; off <<= 1) {
#pragma unroll
      for (int j = 0; j < 9; ++j) acc[j] += __shfl_xor(acc[j], off, 64);
    }
    // new_memory = 4 * memory (bulk case; K3 fixes the <=32 written rows)
    ((float4*)(out + OFF_NM + rowoff))[q] =
        make_float4(4.f*v.x, 4.f*v.y, 4.f*v.z, 4.f*v.w);
    if (q < 8) {
      float m_norm = fmaxf(sqrtf(acc[8]), EPSV);
      sims[q][it * 16 + g] = BETA * acc[q] / (knorm[q] * m_norm + EPSV);
    }
  }
  __syncthreads();
#pragma unroll
  for (int h = 0; h < 8; ++h) {
    long long o = (h < 4) ? (OFF_RW + ((long long)(b * 4 + h)) * Nn)
                          : (OFF_WW + ((long long)(b * 4 + h - 4)) * Nn);
    out[o + base + t] = sims[h][t];
  }
}

// ---------------------------------------------------------------------------
// K2: per (b,h,read|write) row of N=8192 sims: extract top-8 (lowest index on
// ties, matching jax.lax.top_k), softmax over the 8 (others are exactly 0 in
// fp32, same as exp(-1e9 - max)), rewrite row = zeros + 8 weights, and emit
// compact (idx, weight) lists to workspace for K3.
// ---------------------------------------------------------------------------
__global__ __launch_bounds__(256) void k2_topk(
    float* __restrict__ out, int* __restrict__ ws_idx, float* __restrict__ ws_wt)
{
  const int blk = blockIdx.x;  // [0,1024): first 512 read rows, then 512 write
  float* row = out + ((blk < 512) ? (OFF_RW + (long long)blk * Nn)
                                  : (OFF_WW + (long long)(blk - 512) * Nn));
  const int t = threadIdx.x;
  float v[32];
#pragma unroll
  for (int i = 0; i < 32; ++i) v[i] = row[t + i * 256];

  __shared__ float lval[4]; __shared__ int lidx[4];
  __shared__ float wval[8]; __shared__ int widx[8];
  __shared__ float wts[8];

  for (int k = 0; k < 8; ++k) {
    float bv = v[0]; int bs = 0;
#pragma unroll
    for (int i = 1; i < 32; ++i) if (v[i] > bv) { bv = v[i]; bs = i; }
    int bi = t + bs * 256;
#pragma unroll
    for (int off = 1; off < 64; off <<= 1) {
      float ov = __shfl_xor(bv, off, 64);
      int   oi = __shfl_xor(bi, off, 64);
      if (ov > bv || (ov == bv && oi < bi)) { bv = ov; bi = oi; }
    }
    if ((t & 63) == 0) { lval[t >> 6] = bv; lidx[t >> 6] = bi; }
    __syncthreads();
    if (t == 0) {
      float best = lval[0]; int bidx = lidx[0];
      for (int j = 1; j < 4; ++j)
        if (lval[j] > best || (lval[j] == best && lidx[j] < bidx)) {
          best = lval[j]; bidx = lidx[j];
        }
      wval[k] = best; widx[k] = bidx;
    }
    __syncthreads();
    const int gi = widx[k];
    // static unroll keeps v[] in VGPRs (no dynamic-index scratch spill)
#pragma unroll
    for (int i = 0; i < 32; ++i)
      if (gi == t + i * 256) v[i] = -3.0e38f;
    __syncthreads();
  }

  if (t == 0) {
    float m = wval[0], den = 0.f, e[8];
    for (int j = 0; j < 8; ++j) { e[j] = expf(wval[j] - m); den += e[j]; }
    for (int j = 0; j < 8; ++j) wts[j] = e[j] / den;
  }
  // zero the whole row, then scatter the 8 weights
  float4* row4 = (float4*)row;
#pragma unroll
  for (int i = 0; i < 8; ++i) row4[t + i * 256] = make_float4(0.f, 0.f, 0.f, 0.f);
  __syncthreads();
  if (t < 8) {
    row[widx[t]] = wts[t];
    ws_idx[blk * 8 + t] = widx[t];
    ws_wt[blk * 8 + t] = wts[t];
  }
}

// ---------------------------------------------------------------------------
// K3: per batch b (64 threads = D lanes):
//  - read_combined[b,:] = 0.25 * sum over 32 (h,e) read entries of w * mem row
//  - for each unique write-selected row n: new_mem = mem*(4 - E) + A where
//    E,A sum contributions of all heads that picked n (duplicate-safe).
// ---------------------------------------------------------------------------
__global__ __launch_bounds__(64) void k3_apply(
    const float* __restrict__ mem, const float* __restrict__ wvals,
    const float* __restrict__ erase, const int* __restrict__ ws_idx,
    const float* __restrict__ ws_wt, float* __restrict__ out)
{
  const int b = blockIdx.x;
  const int t = threadIdx.x;  // d index

  float acc = 0.f;
  for (int e = 0; e < 32; ++e) {
    int n   = ws_idx[b * 32 + e];
    float w = ws_wt[b * 32 + e];
    acc += w * mem[((long long)b * Nn + n) * Dd + t];
  }
  out[OFF_RC + b * 64 + t] = 0.25f * acc;

  int nn[32]; float wwt[32];
#pragma unroll
  for (int e = 0; e < 32; ++e) {
    nn[e]  = ws_idx[4096 + b * 32 + e];
    wwt[e] = ws_wt[4096 + b * 32 + e];
  }
  for (int e = 0; e < 32; ++e) {
    int n = nn[e];
    bool first = true;
    for (int j = 0; j < e; ++j) if (nn[j] == n) first = false;
    if (!first) continue;   // uniform branch: nn identical across threads
    float E = 0.f, A = 0.f;
    for (int j = e; j < 32; ++j) if (nn[j] == n) {
      int h = j >> 3;
      E += wwt[j] * erase[((long long)b * 4 + h) * 64 + t];
      A += wwt[j] * wvals[((long long)b * 4 + h) * 64 + t];
    }
    float m = mem[((long long)b * Nn + n) * Dd + t];
    out[OFF_NM + ((long long)b * Nn + n) * Dd + t] = m * (4.f - E) + A;
  }
}

extern "C" void kernel_launch(void* const* d_in, const int* in_sizes, int n_in,
                              void* d_out, int out_size, void* d_ws, size_t ws_size,
                              hipStream_t stream) {
  (void)in_sizes; (void)n_in; (void)out_size; (void)ws_size;
  const float* mem   = (const float*)d_in[0];
  const float* rkeys = (const float*)d_in[1];
  const float* wkeys = (const float*)d_in[2];
  const float* wvals = (const float*)d_in[3];
  const float* erase = (const float*)d_in[4];
  float* out = (float*)d_out;
  int*   ws_idx = (int*)d_ws;                                  // 8192 ints
  float* ws_wt  = (float*)((char*)d_ws + 8192 * sizeof(int));  // 8192 floats

  hipLaunchKernelGGL(k1_sims, dim3(Bb * 32), dim3(256), 0, stream,
                     mem, rkeys, wkeys, out);
  hipLaunchKernelGGL(k2_topk, dim3(1024), dim3(256), 0, stream,
                     out, ws_idx, ws_wt);
  hipLaunchKernelGGL(k3_apply, dim3(Bb), dim3(64), 0, stream,
                     mem, wvals, erase, ws_idx, ws_wt, out);
}